// Round 14
// baseline (147.732 us; speedup 1.0000x reference)
//
#include <hip/hip_runtime.h>
#include <hip/hip_bf16.h>
#include <hip/hip_fp16.h>
#include <math.h>

// B=4, T=4096, C=1024, H=64 attention head, scores = K@Q^T, causal, softmax over s.
// R23: proj co-residency -0.8us (146.4). Fill-kernel byte count (256MiB exact)
// identifies the ~90us fixed gap as in-graph workspace re-poison — uncontrollable.
// R24 (this round): cut controllable bytes. (a) Pb partial slabs f32 -> fp16
// (positive-weight sums, no cross-chunk cancellation; +<=1e-3 abs err vs 6.1e-2
// threshold): 37.8 -> 18.9 MB round trip. (b) k==1 tiles (tt<8): attn normalizes
// in-register (merged ln via LDS, fence-free) and writes out directly; reduce_norm
// shrinks to 224 blocks (tiles 8-63). Keep: fragment-native K/Q/V, S-pipeline,
// XCD remap, proj BM=32, setprio, raw v_exp, native cvt.

typedef __attribute__((ext_vector_type(8))) short bf16x8;
typedef __attribute__((ext_vector_type(4))) short bf16x4;
typedef __attribute__((ext_vector_type(4))) float f32x4;
typedef __attribute__((ext_vector_type(8))) _Float16 halfx8;
typedef __attribute__((ext_vector_type(4))) _Float16 halfx4;

#define MFMA16(a, b, c) __builtin_amdgcn_mfma_f32_16x16x32_bf16(a, b, c, 0, 0, 0)

__device__ __forceinline__ short f2bf(float f) {
    __hip_bfloat16 h = __float2bfloat16(f);    // RNE; lowers to v_cvt_pk_bf16_f32
    return *reinterpret_cast<short*>(&h);
}

#if __has_builtin(__builtin_amdgcn_exp2f)
__device__ __forceinline__ float fexp2(float x) { return __builtin_amdgcn_exp2f(x); }
#else
__device__ __forceinline__ float fexp2(float x) { return exp2f(x); }
#endif

static constexpr int T = 4096;
static constexpr int C = 1024;
static constexpr int H = 64;
static constexpr int BATCH = 4;
static constexpr int M = BATCH * T;
static constexpr int CPB = 288;            // chunks per batch at CH=8 s-tiles/chunk
static constexpr float LOG2E = 1.44269504088896340736f;
static constexpr float KSCALE = 0.03125f * LOG2E;  // C^-0.5 * log2(e), folded into K

// Fragment layout per 64x64 tile (4096 shorts): off = sub16*1024 + half*512 +
// lane*8 + j. K/Q: sub16=row/16, (half,q,j) from h: half=h>>5, q=(h&31)>>3, j=h&7,
// lane=q*16+(row&15). V: sub16=h/16, half=s>>5, q=(s&31)>>3, j=s&7, lane=q*16+(h&15).

// ---------------------------------------------------------------------------
// Kernel 1: W -> bf16 transposed [192][1024] (LDS transpose). 48 blocks.
// ---------------------------------------------------------------------------
__global__ __launch_bounds__(256) void wtrans_kernel(
    const float* __restrict__ Wk, const float* __restrict__ Wq,
    const float* __restrict__ Wv, short* __restrict__ Wt_g)
{
    const int blk = blockIdx.x;
    const int tid = threadIdx.x;
    __shared__ short Wl[64][72];
    const int mat = blk / 16, k0 = (blk % 16) * 64;
    const float* W = (mat == 0) ? Wk : (mat == 1) ? Wq : Wv;
    const int hr = (tid & 15) * 4, kr = tid >> 4;
    #pragma unroll
    for (int pass = 0; pass < 4; ++pass) {
        int k = kr + pass * 16;
        float4 v = *(const float4*)&W[(size_t)(k0 + k) * H + hr];
        Wl[hr + 0][k] = f2bf(v.x);
        Wl[hr + 1][k] = f2bf(v.y);
        Wl[hr + 2][k] = f2bf(v.z);
        Wl[hr + 3][k] = f2bf(v.w);
    }
    __syncthreads();
    const int h = tid >> 2, kk = (tid & 3) * 16;
    bf16x8 o0 = *(const bf16x8*)&Wl[h][kk];
    bf16x8 o1 = *(const bf16x8*)&Wl[h][kk + 8];
    *(bf16x8*)&Wt_g[(size_t)(mat * 64 + h) * C + k0 + kk] = o0;
    *(bf16x8*)&Wt_g[(size_t)(mat * 64 + h) * C + k0 + kk + 8] = o1;
}

// ---------------------------------------------------------------------------
// Kernel 2: fused projection, BM=32, 256 threads, 512 blocks (2 blocks/CU).
// 4 waves = 2 row-strips (w2) x 2 col-groups (grp). Double-buffered LDS.
// Epilogue stages the half-tile in dead Ws[0], then coalesced 16B stores.
// ---------------------------------------------------------------------------
__global__ __launch_bounds__(256) void proj_kernel(
    const float* __restrict__ x, const short* __restrict__ Wt_g,
    const float* __restrict__ bk, const float* __restrict__ bq,
    const float* __restrict__ bv,
    short* __restrict__ Kf, short* __restrict__ Qf, short* __restrict__ Vf)
{
    __shared__ short As[2][32][72];
    __shared__ short Ws[2][192][72];
    const int tid = threadIdx.x;
    const int wv = tid >> 6, lane = tid & 63, quad = lane >> 4, l16 = lane & 15;
    const int grp = wv >> 1, w2 = wv & 1;
    const int m0 = blockIdx.x * 32;
    const int arow = tid >> 3, ac8 = (tid & 7) * 8;   // 32 rows x 8 thr/row

    f32x4 acc[6];
    #pragma unroll
    for (int i = 0; i < 6; ++i)
        for (int j = 0; j < 4; ++j) acc[i][j] = 0.f;

    float4 xa0, xa1;
    bf16x8 wl[6];
    auto gload = [&](int k0) {
        xa0 = *(const float4*)&x[(size_t)(m0 + arow) * C + k0 + ac8];
        xa1 = *(const float4*)&x[(size_t)(m0 + arow) * C + k0 + ac8 + 4];
        #pragma unroll
        for (int i = 0; i < 6; ++i) {
            int idx = tid + i * 256;                 // 0..1535 = 192 rows x 8
            wl[i] = *(const bf16x8*)&Wt_g[(size_t)(idx >> 3) * C + k0 + (idx & 7) * 8];
        }
    };
    auto lwrite = [&](int p) {
        bf16x8 av;
        av[0] = f2bf(xa0.x); av[1] = f2bf(xa0.y); av[2] = f2bf(xa0.z); av[3] = f2bf(xa0.w);
        av[4] = f2bf(xa1.x); av[5] = f2bf(xa1.y); av[6] = f2bf(xa1.z); av[7] = f2bf(xa1.w);
        *(bf16x8*)&As[p][arow][ac8] = av;
        #pragma unroll
        for (int i = 0; i < 6; ++i) {
            int idx = tid + i * 256;
            *(bf16x8*)&Ws[p][idx >> 3][(idx & 7) * 8] = wl[i];
        }
    };

    gload(0);
    lwrite(0);
    __syncthreads();
    for (int it = 0; it < 16; ++it) {
        const int p = it & 1;
        if (it < 15) gload((it + 1) * 64);
        bf16x8 a0 = *(const bf16x8*)&As[p][w2 * 16 + l16][quad * 8];
        bf16x8 a1 = *(const bf16x8*)&As[p][w2 * 16 + l16][32 + quad * 8];
        #pragma unroll
        for (int tn = 0; tn < 6; ++tn) {
            bf16x8 b0 = *(const bf16x8*)&Ws[p][grp * 96 + tn * 16 + l16][quad * 8];
            bf16x8 b1 = *(const bf16x8*)&Ws[p][grp * 96 + tn * 16 + l16][32 + quad * 8];
            acc[tn] = MFMA16(a0, b0, acc[tn]);
            acc[tn] = MFMA16(a1, b1, acc[tn]);
        }
        if (it < 15) {
            lwrite((it + 1) & 1);
            __syncthreads();
        }
    }
    // ---- epilogue: stage half-tile fragment-order into dead Ws[0] (6144 shorts).
    const int tile = blockIdx.x >> 1, bh = blockIdx.x & 1;
    short* stage = &Ws[0][0][0];
    #pragma unroll
    for (int tn = 0; tn < 6; ++tn) {
        int gc = grp * 96 + tn * 16 + l16;
        int mat = gc >> 6, h = gc & 63;
        const float* bias = (mat == 0) ? bk : (mat == 1) ? bq : bv;
        float bb = bias[h];
        float sc = (mat == 0) ? KSCALE : 1.f;
        #pragma unroll
        for (int r = 0; r < 4; ++r) {
            int s = w2 * 16 + quad * 4 + r;          // row within 32-half [0,32)
            short val = f2bf((acc[tn][r] + bb) * sc);
            int o;
            if (mat == 2) {
                o = 4096 + (h >> 4) * 512 + (((s >> 3) * 16) + (h & 15)) * 8 + (s & 7);
            } else {
                o = mat * 2048 + (s >> 4) * 1024 + (h >> 5) * 512
                    + ((((h & 31) >> 3) * 16) + (s & 15)) * 8 + (h & 7);
            }
            stage[o] = val;
        }
    }
    __syncthreads();
    {
        int voff = tid * 8;                          // [0,2048)
        *(bf16x8*)&Kf[(size_t)tile * 4096 + bh * 2048 + voff] =
            *(const bf16x8*)&stage[voff];
        *(bf16x8*)&Qf[(size_t)tile * 4096 + bh * 2048 + voff] =
            *(const bf16x8*)&stage[2048 + voff];
        int hn = tid >> 6, u = voff & 511;           // 4 runs of 512
        *(bf16x8*)&Vf[(size_t)tile * 4096 + hn * 1024 + bh * 512 + u] =
            *(const bf16x8*)&stage[4096 + voff];
    }
}

// ---------------------------------------------------------------------------
// Kernel 3: flash attention partial, software-pipelined, XCD-locality remapped.
// fp16 partial slabs; k==1 tiles normalize in-register and write out directly.
// 4 waves/block; wave = (sh, sp). NO ATOMICS, NO FENCES.
// ---------------------------------------------------------------------------
__global__ __launch_bounds__(256) void attn_part_kernel(
    const short* __restrict__ Kf, const short* __restrict__ Qf,
    const short* __restrict__ Vf, _Float16* __restrict__ Pb,
    float* __restrict__ lnPb, float* __restrict__ out)
{
    __shared__ short Pl[4][2][16][76];         // [wave][strip][t16][s]
    __shared__ float Ob[64][68];               // merge buffer (16B-aligned rows)
    __shared__ float lnb[64];
    const int tid = threadIdx.x;
    const int wv = tid >> 6, lane = tid & 63;
    const int quad = lane >> 4, l16 = lane & 15;
    const int sp = wv & 1, sh = wv >> 1;       // strip-pair, s-half
    const int g = blockIdx.x;                  // 0..1151
    const int x = g & 7;                       // target XCD (blockIdx%8 heuristic)
    const int i = g >> 3;                      // 0..143 within XCD
    const int b = x >> 1;                      // one batch per XCD pair
    int tt, chi;
    if ((x & 1) == 0) {                        // chunk-offsets {0,1,6,7}
        if (i < 64)       { chi = 0; tt = i; }
        else if (i < 120) { chi = 1; tt = 8 + (i - 64); }
        else if (i < 136) { chi = 6; tt = 48 + (i - 120); }
        else              { chi = 7; tt = 56 + (i - 136); }
    } else {                                   // chunk-offsets {2,3,4,5}
        if (i < 48)       { chi = 2; tt = 16 + i; }
        else if (i < 88)  { chi = 3; tt = 24 + (i - 48); }
        else if (i < 120) { chi = 4; tt = 32 + (i - 88); }
        else              { chi = 5; tt = 40 + (i - 120); }
    }
    const int kch = tt / 8 + 1;                // chunks for this tile
    const int c = 4 * kch * (kch - 1) + (tt - 8 * (kch - 1)) * kch + chi;
    const int sA = sp * 2, sB = sp * 2 + 1;    // this wave's two strips (t-sub16s)
    const int st0 = chi * 8;
    const int st1 = min(st0 + 8, tt + 1);

    // K fragments: contiguous 1KB bursts at lane*8 shorts
    const short* kt = Kf + (size_t)(b * 64 + tt) * 4096 + lane * 8;
    bf16x8 kf0a = *(const bf16x8*)(kt + sA * 1024);
    bf16x8 kf1a = *(const bf16x8*)(kt + sA * 1024 + 512);
    bf16x8 kf0b = *(const bf16x8*)(kt + sB * 1024);
    bf16x8 kf1b = *(const bf16x8*)(kt + sB * 1024 + 512);

    bf16x8 ones;
    #pragma unroll
    for (int j = 0; j < 8; ++j) ones[j] = (short)0x3F80;   // bf16 1.0

    f32x4 oA[4], oB[4], lnA, lnB;
    #pragma unroll
    for (int i2 = 0; i2 < 4; ++i2)
        for (int j = 0; j < 4; ++j) { oA[i2][j] = 0.f; oB[i2][j] = 0.f; }
    #pragma unroll
    for (int j = 0; j < 4; ++j) { lnA[j] = 0.f; lnB[j] = 0.f; }

    // this wave's s-tiles: st0+sh, st0+sh+2, ... (interleaved for balance)
    const int myb = st0 + sh;
    const short* qp = Qf + (size_t)(b * 64 + myb) * 4096 + lane * 8;
    const short* vp = Vf + (size_t)(b * 64 + myb) * 4096 + lane * 8;

    bf16x8 qc0[4], qc1[4];
    f32x4 sAc[4], sBc[4];
    // prologue: Q(myb) + S(myb)
    if (myb < st1) {
        #pragma unroll
        for (int tn = 0; tn < 4; ++tn) {
            qc0[tn] = *(const bf16x8*)(qp + tn * 1024);
            qc1[tn] = *(const bf16x8*)(qp + tn * 1024 + 512);
        }
        __builtin_amdgcn_s_setprio(1);
        #pragma unroll
        for (int tn = 0; tn < 4; ++tn) {
            #pragma unroll
            for (int j = 0; j < 4; ++j) { sAc[tn][j] = 0.f; sBc[tn][j] = 0.f; }
            sAc[tn] = MFMA16(qc0[tn], kf0a, sAc[tn]);
            sAc[tn] = MFMA16(qc1[tn], kf1a, sAc[tn]);
            sBc[tn] = MFMA16(qc0[tn], kf0b, sBc[tn]);
            sBc[tn] = MFMA16(qc1[tn], kf1b, sBc[tn]);
        }
        __builtin_amdgcn_s_setprio(0);
    }

    for (int st = myb; st < st1; st += 2) {
        // V(st) fragments (consumed by PV at the end)
        bf16x8 vb0[4], vb1[4];
        #pragma unroll
        for (int hn = 0; hn < 4; ++hn) {
            vb0[hn] = *(const bf16x8*)(vp + hn * 1024);
            vb1[hn] = *(const bf16x8*)(vp + hn * 1024 + 512);
        }
        // Q(st+2) load, issued early — covered by exp/pack below
        const size_t qoff = (st + 2 < st1) ? 8192 : 0;
        #pragma unroll
        for (int tn = 0; tn < 4; ++tn) {
            qc0[tn] = *(const bf16x8*)(qp + qoff + tn * 1024);
            qc1[tn] = *(const bf16x8*)(qp + qoff + tn * 1024 + 512);
        }
        // exp/pack(st) — consumes sAc/sBc (computed last iteration)
        const bool diag = (st == tt);
        #pragma unroll
        for (int tn = 0; tn < 4; ++tn) {
            bf16x4 pa, pb;
            #pragma unroll
            for (int r = 0; r < 4; ++r) {
                float va = sAc[tn][r], vb = sBc[tn][r];
                if (diag) {
                    int scol = tn * 16 + quad * 4 + r;
                    if (scol > sA * 16 + l16) va = -INFINITY;
                    if (scol > sB * 16 + l16) vb = -INFINITY;
                }
                pa[r] = f2bf(fexp2(va));
                pb[r] = f2bf(fexp2(vb));
            }
            *(bf16x4*)&Pl[wv][0][l16][tn * 16 + quad * 4] = pa;
            *(bf16x4*)&Pl[wv][1][l16][tn * 16 + quad * 4] = pb;
        }
        // P read-back (LDS); latency hidden by the S-MFMA cluster below
        bf16x8 aA0 = *(const bf16x8*)&Pl[wv][0][l16][quad * 8];
        bf16x8 aA1 = *(const bf16x8*)&Pl[wv][0][l16][32 + quad * 8];
        bf16x8 aB0 = *(const bf16x8*)&Pl[wv][1][l16][quad * 8];
        bf16x8 aB1 = *(const bf16x8*)&Pl[wv][1][l16][32 + quad * 8];
        // S-MFMA for st+2 (independent of P; sAc/sBc reused after exp)
        if (st + 2 < st1) {
            __builtin_amdgcn_s_setprio(1);
            #pragma unroll
            for (int tn = 0; tn < 4; ++tn) {
                #pragma unroll
                for (int j = 0; j < 4; ++j) { sAc[tn][j] = 0.f; sBc[tn][j] = 0.f; }
                sAc[tn] = MFMA16(qc0[tn], kf0a, sAc[tn]);
                sAc[tn] = MFMA16(qc1[tn], kf1a, sAc[tn]);
                sBc[tn] = MFMA16(qc0[tn], kf0b, sBc[tn]);
                sBc[tn] = MFMA16(qc1[tn], kf1b, sBc[tn]);
            }
            __builtin_amdgcn_s_setprio(0);
        }
        // PV(st) for both strips
        __builtin_amdgcn_s_setprio(1);
        #pragma unroll
        for (int hn = 0; hn < 4; ++hn) {
            oA[hn] = MFMA16(aA0, vb0[hn], oA[hn]);
            oA[hn] = MFMA16(aA1, vb1[hn], oA[hn]);
            oB[hn] = MFMA16(aB0, vb0[hn], oB[hn]);
            oB[hn] = MFMA16(aB1, vb1[hn], oB[hn]);
        }
        lnA = MFMA16(aA0, ones, lnA);
        lnA = MFMA16(aA1, ones, lnA);
        lnB = MFMA16(aB0, ones, lnB);
        lnB = MFMA16(aB1, ones, lnB);
        __builtin_amdgcn_s_setprio(0);
        qp += 8192;
        vp += 8192;
    }

    // s-half merge: sh==1 stages partials; sh==0 adds into Ob; merged ln goes
    // to lnPb (k>1) or back into lnb (k==1, for in-kernel normalize).
    const int rbase = sp * 32;
    if (sh == 1) {
        #pragma unroll
        for (int hn = 0; hn < 4; ++hn)
            #pragma unroll
            for (int r = 0; r < 4; ++r) {
                Ob[rbase + quad * 4 + r][hn * 16 + l16] = oA[hn][r];
                Ob[rbase + 16 + quad * 4 + r][hn * 16 + l16] = oB[hn][r];
            }
        if (l16 == 0) {
            #pragma unroll
            for (int r = 0; r < 4; ++r) {
                lnb[rbase + quad * 4 + r] = lnA[r];
                lnb[rbase + 16 + quad * 4 + r] = lnB[r];
            }
        }
    }
    __syncthreads();
    if (sh == 0) {
        #pragma unroll
        for (int hn = 0; hn < 4; ++hn)
            #pragma unroll
            for (int r = 0; r < 4; ++r) {
                int ra = rbase + quad * 4 + r;
                int rb = ra + 16;
                Ob[ra][hn * 16 + l16] += oA[hn][r];
                Ob[rb][hn * 16 + l16] += oB[hn][r];
            }
        if (l16 == 0) {
            #pragma unroll
            for (int r = 0; r < 4; ++r) {
                float mA = lnA[r] + lnb[rbase + quad * 4 + r];
                float mB = lnB[r] + lnb[rbase + 16 + quad * 4 + r];
                if (kch == 1) {
                    lnb[rbase + quad * 4 + r] = mA;
                    lnb[rbase + 16 + quad * 4 + r] = mB;
                } else {
                    float* lc = lnPb + (size_t)(b * CPB + c) * 64;
                    lc[rbase + quad * 4 + r] = mA;
                    lc[rbase + 16 + quad * 4 + r] = mB;
                }
            }
        }
    }
    __syncthreads();
    if (kch == 1) {
        // single-chunk tile: normalize and write out directly (no partials)
        float* ob = out + (size_t)(b * T + tt * 64) * H;
        #pragma unroll
        for (int i2 = 0; i2 < 4; ++i2) {
            int idx = tid + i2 * 256;              // 0..1023 float4 index
            int row = idx >> 4, c4 = (idx & 15) * 4;
            float inv = 1.f / lnb[row];
            float4 v = *(const float4*)&Ob[row][c4];
            v.x *= inv; v.y *= inv; v.z *= inv; v.w *= inv;
            *(float4*)&ob[row * H + c4] = v;
        }
    } else {
        // fp16 slab store (coalesced 16B per thread-pass)
        _Float16* Pc = Pb + (size_t)(b * CPB + c) * 4096;
        #pragma unroll
        for (int i2 = 0; i2 < 2; ++i2) {
            int idx = tid + i2 * 256;              // 0..511, 8 halves each
            int row = idx >> 3, c8 = (idx & 7) * 8;
            halfx8 hv;
            #pragma unroll
            for (int j = 0; j < 8; ++j) hv[j] = (_Float16)Ob[row][c8 + j];
            *(halfx8*)&Pc[idx * 8] = hv;
        }
    }
}

// ---------------------------------------------------------------------------
// Kernel 4: reduce 2..8 contiguous fp16 chunk partials per t-tile (tt>=8),
// normalize, write out. Grid: BATCH*56 blocks of 256 threads.
// ---------------------------------------------------------------------------
__global__ __launch_bounds__(256) void reduce_norm_kernel(
    const _Float16* __restrict__ Pb, const float* __restrict__ lnPb,
    float* __restrict__ out)
{
    const int blk = blockIdx.x;                // b*56 + (tt-8)
    const int b = blk / 56, tt = 8 + blk % 56;
    const int k = tt / 8 + 1;                  // number of chunk partials (>=2)
    const int base_c = 4 * k * (k - 1) + (tt - 8 * (k - 1)) * k;
    const int tid = threadIdx.x;
    __shared__ float lnS[64];
    if (tid < 64) {
        float s = 0.f;
        for (int i = 0; i < k; ++i)
            s += lnPb[(size_t)(b * CPB + base_c + i) * 64 + tid];
        lnS[tid] = 1.f / s;
    }
    __syncthreads();
    float4 acc[4];
    #pragma unroll
    for (int j = 0; j < 4; ++j) acc[j] = {0.f, 0.f, 0.f, 0.f};
    for (int i = 0; i < k; ++i) {
        const _Float16* p = Pb + (size_t)(b * CPB + base_c + i) * 4096;
        #pragma unroll
        for (int j = 0; j < 4; ++j) {
            halfx4 hv = *(const halfx4*)&p[(tid + j * 256) * 4];
            acc[j].x += (float)hv[0]; acc[j].y += (float)hv[1];
            acc[j].z += (float)hv[2]; acc[j].w += (float)hv[3];
        }
    }
    float4* o4 = (float4*)out;
    const size_t obase = ((size_t)b * T + (size_t)tt * 64) * 16;   // float4 units
    #pragma unroll
    for (int j = 0; j < 4; ++j) {
        int idx = tid + j * 256;               // float4 index within 64x64 tile
        float inv = lnS[idx >> 4];             // 16 float4 per row
        float4 v = acc[j];
        v.x *= inv; v.y *= inv; v.z *= inv; v.w *= inv;
        o4[obase + idx] = v;
    }
}

// ---------------------------------------------------------------------------
extern "C" void kernel_launch(void* const* d_in, const int* in_sizes, int n_in,
                              void* d_out, int out_size, void* d_ws, size_t ws_size,
                              hipStream_t stream) {
    const float* x  = (const float*)d_in[0];
    const float* Wk = (const float*)d_in[1];
    const float* bk = (const float*)d_in[2];
    const float* Wq = (const float*)d_in[3];
    const float* bq = (const float*)d_in[4];
    const float* Wv = (const float*)d_in[5];
    const float* bv = (const float*)d_in[6];
    float* out = (float*)d_out;

    char* ws = (char*)d_ws;
    size_t off = 0;
    short* Kf      = (short*)(ws + off);    off += (size_t)M * H * 2;          // 2 MB
    short* Qf      = (short*)(ws + off);    off += (size_t)M * H * 2;          // 2 MB
    short* Vf      = (short*)(ws + off);    off += (size_t)M * H * 2;          // 2 MB
    short* Wt_g    = (short*)(ws + off);    off += (size_t)192 * C * 2;        // 384 KB
    _Float16* Pb   = (_Float16*)(ws + off); off += (size_t)BATCH * CPB * 4096 * 2; // 9.4 MB
    float* lnPb    = (float*)(ws + off);    off += (size_t)BATCH * CPB * 64 * 4;   // 295 KB
    // total ~16.1 MB

    wtrans_kernel<<<48, 256, 0, stream>>>(Wk, Wq, Wv, Wt_g);
    proj_kernel<<<M / 32, 256, 0, stream>>>(x, Wt_g, bk, bq, bv, Kf, Qf, Vf);
    attn_part_kernel<<<BATCH * CPB, 256, 0, stream>>>(Kf, Qf, Vf, Pb, lnPb, out);
    reduce_norm_kernel<<<BATCH * 56, 256, 0, stream>>>(Pb, lnPb, out);
}